// Round 8
// baseline (1029.090 us; speedup 1.0000x reference)
//
#include <hip/hip_runtime.h>
#include <math.h>

#define O_CH 32
#define I_CH 3
#define IH 512
#define IW 512
#define OH 510
#define OW 510
#define N_IMG 16
#define WSTRIDE 32       // weight row stride in d_ws

typedef float v2f __attribute__((ext_vector_type(2)));
typedef float v4f __attribute__((ext_vector_type(4)));

__global__ __launch_bounds__(256) void gabor_weights_kernel(
    const float* __restrict__ freq, const float* __restrict__ theta,
    const float* __restrict__ psi, const float* __restrict__ sigma,
    float* __restrict__ wp) {
  int idx = blockIdx.x * 256 + threadIdx.x;
  if (idx >= O_CH * I_CH * 9) return;
  int o = idx / 27;
  int rem = idx % 27;          // rem = c*9 + kh*3 + kw
  int kh = (rem / 3) % 3;
  int kw = rem % 3;
  // linspace(-ceil(3/2)+1, ceil(3/2), 3) = {-1, 0.5, 2}
  float x = (kw == 0) ? -1.0f : (kw == 1 ? 0.5f : 2.0f);
  float y = (kh == 0) ? -1.0f : (kh == 1 ? 0.5f : 2.0f);
  int pi = o * I_CH + rem / 9; // (O,I) parameter index
  float th = theta[pi], f = freq[pi], p = psi[pi], s = sigma[pi];
  float ct = cosf(th), st = sinf(th);
  float rotx = x * ct + y * st;
  float roty = -x * st + y * ct;
  float se = s + 0.001f;
  float g = expf(-0.5f * (rotx * rotx + roty * roty) / (se * se));
  g *= cosf(f * rotx + p);
  g /= (2.0f * 3.14f * s * s);   // reference uses PI = 3.14 exactly
  wp[o * WSTRIDE + rem] = g;
}

// R4-family structure (lane computes ALL 32 o per loaded window — R6 proved
// dropping this costs 2.6x), tuned for occupancy: lane owns 4 px x 1 row ->
// window = 3c x 3r x 6cols = 54 floats, acc 4 -> ~80 VGPR -> 6 waves/SIMD
// (mild launch_bounds(256,6); R5's failure was forcing 8 on a 90-float
// window). 4080 blocks = 16/CU smooths the occupancy tail (R4: 8/CU in 2
// ragged generations). Even rows: one dense 16B dwordx4 store; odd rows 2x8B.
// XCD chunk swizzle: q=510 -> 2 images per XCD, rows in order (halo L2 reuse).
__global__ __launch_bounds__(256, 6) void gabor_conv_kernel(
    const float* __restrict__ in, const float* __restrict__ wgp,
    float* __restrict__ out) {
  // Weights per (o,c) padded to 12 floats (float4-aligned rows)
  __shared__ float sW[O_CH][I_CH * 12];

  const int tid = threadIdx.x;
  for (int i = tid; i < O_CH * I_CH * 12; i += 256) {
    int o = i / 36;
    int t = i % 36;
    int c = t / 12;
    int j = t % 12;
    sW[o][t] = (j < 9) ? wgp[o * WSTRIDE + c * 9 + j] : 0.0f;
  }
  __syncthreads();

  const int wv = tid >> 6;     // 0..3
  const int lane = tid & 63;

  // chunked XCD swizzle (bijective: 4080 % 8 == 0, q = 510 = 2 images)
  const int bid = blockIdx.x;
  const int q = gridDim.x >> 3;
  const int nid = (bid & 7) * q + (bid >> 3);
  const int n  = nid / 255;            // image 0..15
  const int rp = nid % 255;            // row-pair 0..254
  const int y0 = rp * 2;               // rows y0, y0+1 (<=509)

  const int row = y0 + (wv & 1);       // this wave's output row
  const int x0 = ((wv >> 1) << 8) + lane * 4;   // 0..252 / 256..508

  const float* inN = in + (size_t)n * I_CH * IH * IW;

  // Input window: 3 ch x 3 rows x 6 cols = 54 VGPRs (rows row..row+2 <= 511)
  float r[I_CH][3][6];
#pragma unroll
  for (int c = 0; c < I_CH; ++c) {
#pragma unroll
    for (int kh = 0; kh < 3; ++kh) {
      const float* rowp = inN + ((size_t)c * IH + row + kh) * IW;
      v4f A = *(const v4f*)&rowp[x0];          // 16B aligned, cols x0..x0+3
      int xc = x0 + 4; if (xc > IW - 2) xc = IW - 2;   // lane63/xh1 clamp
      v2f B = *(const v2f*)&rowp[xc];
      r[c][kh][0] = A.x; r[c][kh][1] = A.y; r[c][kh][2] = A.z; r[c][kh][3] = A.w;
      r[c][kh][4] = B.x; r[c][kh][5] = B.y;
    }
  }

  const bool full = (x0 + 4 <= OW);   // false only for x0 == 508
  const bool evenRow = ((row & 1) == 0);
  float* outP = out + ((size_t)n * O_CH) * (OH * OW) + (size_t)row * OW + x0;

#define FMA4(kh, kw, W)                          \
  a0 = fmaf(r[c][kh][kw + 0], (W), a0);          \
  a1 = fmaf(r[c][kh][kw + 1], (W), a1);          \
  a2 = fmaf(r[c][kh][kw + 2], (W), a2);          \
  a3 = fmaf(r[c][kh][kw + 3], (W), a3);

#pragma unroll 2
  for (int o = 0; o < O_CH; ++o) {
    float a0 = 0.f, a1 = 0.f, a2 = 0.f, a3 = 0.f;
#pragma unroll
    for (int c = 0; c < I_CH; ++c) {
      const v4f* w4 = (const v4f*)&sW[o][c * 12];   // 3x broadcast ds_read_b128
      v4f w0 = w4[0], w1 = w4[1], w2 = w4[2];
      FMA4(0, 0, w0.x); FMA4(0, 1, w0.y); FMA4(0, 2, w0.z);
      FMA4(1, 0, w0.w); FMA4(1, 1, w1.x); FMA4(1, 2, w1.y);
      FMA4(2, 0, w1.z); FMA4(2, 1, w1.w); FMA4(2, 2, w2.x);
    }
    float* op = outP + (size_t)o * (OH * OW);
    if (full) {
      if (evenRow) {
        *(v4f*)op = (v4f){a0, a1, a2, a3};        // ob%4==0: 16B aligned
      } else {
        *(v2f*)op       = (v2f){a0, a1};          // ob%4==2: 8B aligned
        *(v2f*)(op + 2) = (v2f){a2, a3};
      }
    } else {
      *(v2f*)op = (v2f){a0, a1};                  // x0==508: px 508,509 only
    }
  }
#undef FMA4
}

extern "C" void kernel_launch(void* const* d_in, const int* in_sizes, int n_in,
                              void* d_out, int out_size, void* d_ws, size_t ws_size,
                              hipStream_t stream) {
  const float* img   = (const float*)d_in[0];
  const float* freq  = (const float*)d_in[1];
  const float* theta = (const float*)d_in[2];
  const float* psi   = (const float*)d_in[3];
  const float* sigma = (const float*)d_in[4];
  float* outp = (float*)d_out;
  float* wgp = (float*)d_ws;  // 32x32 floats of scratch (Gabor weights)

  gabor_weights_kernel<<<dim3(4), dim3(256), 0, stream>>>(freq, theta, psi, sigma, wgp);

  dim3 grid(N_IMG * 255);   // 4080 blocks; block = one row-pair, 4 waves
  gabor_conv_kernel<<<grid, dim3(256), 0, stream>>>(img, wgp, outp);
}

// Round 9
// 162.646 us; speedup vs baseline: 6.3272x; 6.3272x over previous
//
#include <hip/hip_runtime.h>
#include <math.h>

#define O_CH 32
#define I_CH 3
#define IH 512
#define IW 512
#define OH 510
#define OW 510
#define N_IMG 16
#define WSTRIDE 32       // weight row stride in d_ws

typedef float v2f __attribute__((ext_vector_type(2)));
typedef float v4f __attribute__((ext_vector_type(4)));

__global__ __launch_bounds__(256) void gabor_weights_kernel(
    const float* __restrict__ freq, const float* __restrict__ theta,
    const float* __restrict__ psi, const float* __restrict__ sigma,
    float* __restrict__ wp) {
  int idx = blockIdx.x * 256 + threadIdx.x;
  if (idx >= O_CH * I_CH * 9) return;
  int o = idx / 27;
  int rem = idx % 27;          // rem = c*9 + kh*3 + kw
  int kh = (rem / 3) % 3;
  int kw = rem % 3;
  // linspace(-ceil(3/2)+1, ceil(3/2), 3) = {-1, 0.5, 2}
  float x = (kw == 0) ? -1.0f : (kw == 1 ? 0.5f : 2.0f);
  float y = (kh == 0) ? -1.0f : (kh == 1 ? 0.5f : 2.0f);
  int pi = o * I_CH + rem / 9; // (O,I) parameter index
  float th = theta[pi], f = freq[pi], p = psi[pi], s = sigma[pi];
  float ct = cosf(th), st = sinf(th);
  float rotx = x * ct + y * st;
  float roty = -x * st + y * ct;
  float se = s + 0.001f;
  float g = expf(-0.5f * (rotx * rotx + roty * roty) / (se * se));
  g *= cosf(f * rotx + p);
  g /= (2.0f * 3.14f * s * s);   // reference uses PI = 3.14 exactly
  wp[o * WSTRIDE + rem] = g;
}

// R4-family structure (lane computes ALL 32 o per register-held window — R6
// proved dropping this costs 2.6x). Lane owns 4 px x 1 row -> window = 3c x
// 3r x 6cols = 54 floats + 4 acc. NO min-waves launch_bounds: R5 (VGPR 32,
// FETCH 1.8GB) and R7 (VGPR 40, FETCH 3.2GB) both proved forcing occupancy
// makes the allocator re-fetch the window per o — catastrophic. Natural
// allocation here should land ~75-90 VGPR -> 5-6 waves/SIMD earned.
// 4080 blocks (~16/CU) smooths the occupancy tail. Even rows: one dense 16B
// dwordx4 store; odd rows 2x8B. XCD chunk swizzle: q=510 -> 2 images/XCD.
__global__ __launch_bounds__(256) void gabor_conv_kernel(
    const float* __restrict__ in, const float* __restrict__ wgp,
    float* __restrict__ out) {
  // Weights per (o,c) padded to 12 floats (float4-aligned rows)
  __shared__ float sW[O_CH][I_CH * 12];

  const int tid = threadIdx.x;
  for (int i = tid; i < O_CH * I_CH * 12; i += 256) {
    int o = i / 36;
    int t = i % 36;
    int c = t / 12;
    int j = t % 12;
    sW[o][t] = (j < 9) ? wgp[o * WSTRIDE + c * 9 + j] : 0.0f;
  }
  __syncthreads();

  const int wv = tid >> 6;     // 0..3
  const int lane = tid & 63;

  // chunked XCD swizzle (bijective: 4080 % 8 == 0, q = 510 = 2 images)
  const int bid = blockIdx.x;
  const int q = gridDim.x >> 3;
  const int nid = (bid & 7) * q + (bid >> 3);
  const int n  = nid / 255;            // image 0..15
  const int rp = nid % 255;            // row-pair 0..254
  const int y0 = rp * 2;               // rows y0, y0+1 (<=509)

  const int row = y0 + (wv & 1);       // this wave's output row
  const int x0 = ((wv >> 1) << 8) + lane * 4;   // 0..252 / 256..508

  const float* inN = in + (size_t)n * I_CH * IH * IW;

  // Input window: 3 ch x 3 rows x 6 cols = 54 VGPRs (rows row..row+2 <= 511)
  float r[I_CH][3][6];
#pragma unroll
  for (int c = 0; c < I_CH; ++c) {
#pragma unroll
    for (int kh = 0; kh < 3; ++kh) {
      const float* rowp = inN + ((size_t)c * IH + row + kh) * IW;
      v4f A = *(const v4f*)&rowp[x0];          // 16B aligned, cols x0..x0+3
      int xc = x0 + 4; if (xc > IW - 2) xc = IW - 2;   // clamp only x0==508
      v2f B = *(const v2f*)&rowp[xc];
      r[c][kh][0] = A.x; r[c][kh][1] = A.y; r[c][kh][2] = A.z; r[c][kh][3] = A.w;
      r[c][kh][4] = B.x; r[c][kh][5] = B.y;
    }
  }

  const bool full = (x0 + 4 <= OW);   // false only for x0 == 508
  const bool evenRow = ((row & 1) == 0);
  float* outP = out + ((size_t)n * O_CH) * (OH * OW) + (size_t)row * OW + x0;

#define FMA4(kh, kw, W)                          \
  a0 = fmaf(r[c][kh][kw + 0], (W), a0);          \
  a1 = fmaf(r[c][kh][kw + 1], (W), a1);          \
  a2 = fmaf(r[c][kh][kw + 2], (W), a2);          \
  a3 = fmaf(r[c][kh][kw + 3], (W), a3);

#pragma unroll 2
  for (int o = 0; o < O_CH; ++o) {
    float a0 = 0.f, a1 = 0.f, a2 = 0.f, a3 = 0.f;
#pragma unroll
    for (int c = 0; c < I_CH; ++c) {
      const v4f* w4 = (const v4f*)&sW[o][c * 12];   // 3x broadcast ds_read_b128
      v4f w0 = w4[0], w1 = w4[1], w2 = w4[2];
      FMA4(0, 0, w0.x); FMA4(0, 1, w0.y); FMA4(0, 2, w0.z);
      FMA4(1, 0, w0.w); FMA4(1, 1, w1.x); FMA4(1, 2, w1.y);
      FMA4(2, 0, w1.z); FMA4(2, 1, w1.w); FMA4(2, 2, w2.x);
    }
    float* op = outP + (size_t)o * (OH * OW);
    if (full) {
      if (evenRow) {
        *(v4f*)op = (v4f){a0, a1, a2, a3};        // ob%4==0: 16B aligned
      } else {
        *(v2f*)op       = (v2f){a0, a1};          // ob%4==2: 8B aligned
        *(v2f*)(op + 2) = (v2f){a2, a3};
      }
    } else {
      *(v2f*)op = (v2f){a0, a1};                  // x0==508: px 508,509 only
    }
  }
#undef FMA4
}

extern "C" void kernel_launch(void* const* d_in, const int* in_sizes, int n_in,
                              void* d_out, int out_size, void* d_ws, size_t ws_size,
                              hipStream_t stream) {
  const float* img   = (const float*)d_in[0];
  const float* freq  = (const float*)d_in[1];
  const float* theta = (const float*)d_in[2];
  const float* psi   = (const float*)d_in[3];
  const float* sigma = (const float*)d_in[4];
  float* outp = (float*)d_out;
  float* wgp = (float*)d_ws;  // 32x32 floats of scratch (Gabor weights)

  gabor_weights_kernel<<<dim3(4), dim3(256), 0, stream>>>(freq, theta, psi, sigma, wgp);

  dim3 grid(N_IMG * 255);   // 4080 blocks; block = one row-pair, 4 waves
  gabor_conv_kernel<<<grid, dim3(256), 0, stream>>>(img, wgp, outp);
}

// Round 10
// 132.183 us; speedup vs baseline: 7.7854x; 1.2305x over previous
//
#include <hip/hip_runtime.h>
#include <math.h>

#define O_CH 32
#define I_CH 3
#define IH 512
#define IW 512
#define OH 510
#define OW 510
#define N_IMG 16
#define WSTRIDE 32       // weight row stride in d_ws

typedef float v2f __attribute__((ext_vector_type(2)));
typedef float v4f __attribute__((ext_vector_type(4)));

__global__ __launch_bounds__(256) void gabor_weights_kernel(
    const float* __restrict__ freq, const float* __restrict__ theta,
    const float* __restrict__ psi, const float* __restrict__ sigma,
    float* __restrict__ wp) {
  int idx = blockIdx.x * 256 + threadIdx.x;
  if (idx >= O_CH * I_CH * 9) return;
  int o = idx / 27;
  int rem = idx % 27;          // rem = c*9 + kh*3 + kw
  int kh = (rem / 3) % 3;
  int kw = rem % 3;
  // linspace(-ceil(3/2)+1, ceil(3/2), 3) = {-1, 0.5, 2}
  float x = (kw == 0) ? -1.0f : (kw == 1 ? 0.5f : 2.0f);
  float y = (kh == 0) ? -1.0f : (kh == 1 ? 0.5f : 2.0f);
  int pi = o * I_CH + rem / 9; // (O,I) parameter index
  float th = theta[pi], f = freq[pi], p = psi[pi], s = sigma[pi];
  float ct = cosf(th), st = sinf(th);
  float rotx = x * ct + y * st;
  float roty = -x * st + y * ct;
  float se = s + 0.001f;
  float g = expf(-0.5f * (rotx * rotx + roty * roty) / (se * se));
  g *= cosf(f * rotx + p);
  g /= (2.0f * 3.14f * s * s);   // reference uses PI = 3.14 exactly
  wp[o * WSTRIDE + rem] = g;
}

// Packed-FP32 version of the R4 structure (all 32 o per register window; no
// forced launch_bounds — R5/R7 law). Lane owns 16 px: rows (y, y+1) x cols
// {x0..x0+3} U {x0+256..x0+259}. The v_pk_fma_f32 pair axis = (Left, Right)
// halves: tap inputs are natural (L,R) v2f pairs built once at load (no
// per-tap repacking movs — x-shifted pairs never straddle halves), weights
// splat to both halves. 216 pk-FMA per o vs 432 scalar for the same px.
// Wave = one full 512-col row-pair -> even row y always 16B-aligned dwordx4
// store; all 6 stores per o share ONE address reg (immediate offsets < 4KB).
// XCD chunk swizzle: 1024 blocks, q=128 = exactly 2 images per XCD.
__global__ __launch_bounds__(256) void gabor_conv_kernel(
    const float* __restrict__ in, const float* __restrict__ wgp,
    float* __restrict__ out) {
  __shared__ float sW[O_CH][28];   // 27 weights + pad, 7x float4 per o

  const int tid = threadIdx.x;
  for (int i = tid; i < O_CH * 28; i += 256) {
    int o = i / 28, j = i % 28;
    sW[o][j] = (j < 27) ? wgp[o * WSTRIDE + j] : 0.0f;
  }
  __syncthreads();

  const int wave = tid >> 6;   // 0..3
  const int lane = tid & 63;

  // bijective chunked XCD swizzle: 1024 blocks, 128 per XCD (= 2 images)
  const int bid = blockIdx.x;
  const int nid = (bid & 7) * 128 + (bid >> 3);
  const int n = nid >> 6;                  // image 0..15
  const int y = (nid & 63) * 8 + wave * 2; // even top row of this wave's pair
  if (y + 1 >= OH) return;                 // only tail-block wave 3 (y=510)

  const int x0 = lane * 4;                 // L px x0..x0+3; R px +256
  const float* inN = in + (size_t)n * (I_CH * IH * IW);

  // Window as (L,R) column pairs: 3 ch x 4 rows x 6 cols = 72 v2f
  v2f P[I_CH][4][6];
#pragma unroll
  for (int c = 0; c < I_CH; ++c) {
#pragma unroll
    for (int rw = 0; rw < 4; ++rw) {
      const float* rowp = inN + ((size_t)c * IH + y + rw) * IW;
      v4f LA = *(const v4f*)&rowp[x0];          // cols x0..x0+3 (16B aligned)
      v2f LB = *(const v2f*)&rowp[x0 + 4];      // cols x0+4,x0+5
      v4f RA = *(const v4f*)&rowp[x0 + 256];    // cols x0+256..+259
      int xc = x0 + 260; if (xc > IW - 2) xc = IW - 2;  // lane63: 512 -> 510
      v2f RB = *(const v2f*)&rowp[xc];
      P[c][rw][0] = (v2f){LA.x, RA.x};
      P[c][rw][1] = (v2f){LA.y, RA.y};
      P[c][rw][2] = (v2f){LA.z, RA.z};
      P[c][rw][3] = (v2f){LA.w, RA.w};
      P[c][rw][4] = (v2f){LB.x, RB.x};
      P[c][rw][5] = (v2f){LB.y, RB.y};
    }
  }

  const bool full = (lane != 63);   // lane63 R px 510,511 are OOB
  float* op = out + (((size_t)n * O_CH * OH) + y) * OW + x0;  // o=0, row y, L

#pragma unroll 2
  for (int o = 0; o < O_CH; ++o) {
    float wq[28];
#pragma unroll
    for (int k = 0; k < 7; ++k) {            // 7 broadcast ds_read_b128
      v4f t = *(const v4f*)&sW[o][k * 4];
      wq[4 * k + 0] = t.x; wq[4 * k + 1] = t.y;
      wq[4 * k + 2] = t.z; wq[4 * k + 3] = t.w;
    }
    v2f a0[4], a1[4];
#pragma unroll
    for (int j = 0; j < 4; ++j) { a0[j] = (v2f){0.f, 0.f}; a1[j] = (v2f){0.f, 0.f}; }
#pragma unroll
    for (int c = 0; c < I_CH; ++c) {
#pragma unroll
      for (int kh = 0; kh < 3; ++kh) {
#pragma unroll
        for (int kw = 0; kw < 3; ++kw) {
          float w = wq[c * 9 + kh * 3 + kw];
          v2f wv = (v2f){w, w};
#pragma unroll
          for (int j = 0; j < 4; ++j) {      // 8 v_pk_fma_f32 per tap
            a0[j] = __builtin_elementwise_fma(P[c][kh + 0][kw + j], wv, a0[j]);
            a1[j] = __builtin_elementwise_fma(P[c][kh + 1][kw + j], wv, a1[j]);
          }
        }
      }
    }
    // unpack (L,R) pairs into row-contiguous quads
    v4f L0 = (v4f){a0[0].x, a0[1].x, a0[2].x, a0[3].x};
    v4f R0 = (v4f){a0[0].y, a0[1].y, a0[2].y, a0[3].y};
    v4f L1 = (v4f){a1[0].x, a1[1].x, a1[2].x, a1[3].x};
    v4f R1 = (v4f){a1[0].y, a1[1].y, a1[2].y, a1[3].y};
    // row y: ob%4==0 (y even) -> dwordx4; row y+1: ob%4==2 -> 8B float2
    *(v4f*)op            = L0;
    *(v2f*)(op + OW)     = (v2f){L1.x, L1.y};
    *(v2f*)(op + OW + 2) = (v2f){L1.z, L1.w};
    if (full) {
      *(v4f*)(op + 256)      = R0;
      *(v2f*)(op + OW + 256) = (v2f){R1.x, R1.y};
      *(v2f*)(op + OW + 258) = (v2f){R1.z, R1.w};
    } else {
      *(v2f*)(op + 256)      = (v2f){R0.x, R0.y};   // px 508,509
      *(v2f*)(op + OW + 256) = (v2f){R1.x, R1.y};
    }
    op += (size_t)(OH * OW);
  }
}

extern "C" void kernel_launch(void* const* d_in, const int* in_sizes, int n_in,
                              void* d_out, int out_size, void* d_ws, size_t ws_size,
                              hipStream_t stream) {
  const float* img   = (const float*)d_in[0];
  const float* freq  = (const float*)d_in[1];
  const float* theta = (const float*)d_in[2];
  const float* psi   = (const float*)d_in[3];
  const float* sigma = (const float*)d_in[4];
  float* outp = (float*)d_out;
  float* wgp = (float*)d_ws;  // 32x32 floats of scratch (Gabor weights)

  gabor_weights_kernel<<<dim3(4), dim3(256), 0, stream>>>(freq, theta, psi, sigma, wgp);

  dim3 grid(N_IMG * 64);   // 1024 blocks; block = 8 rows (4 waves x row-pair)
  gabor_conv_kernel<<<grid, dim3(256), 0, stream>>>(img, wgp, outp);
}